// Round 1
// baseline (515.928 us; speedup 1.0000x reference)
//
#include <hip/hip_runtime.h>

// Deformable RoI pooling (MMCV-style), forward only.
// features: (B=8, C=256, H=168, W=168) fp32
// rois:     (N=512, 5)  [bidx, x1, y1, x2, y2]
// offset:   (N=512, 2, PH=7, PW=7)
// out:      (N, C, PH, PW) fp32
//
// Mapping: one 64-thread (1-wave) block per (n, c). Lanes 0..48 cover the
// 7x7 bins; each lane loops 2x2 subsamples (16 gathers). All gathers of a
// block stay within one 112 KB channel plane -> L1/L2 reuse. No barriers.

#define PH_ 7
#define PW_ 7
#define SPP_ 2
#define SS_ 0.0625f
#define TRANS_STD_ 0.1f
#define B_ 8
#define C_ 256
#define H_ 168
#define W_ 168
#define N_ 512

__global__ __launch_bounds__(64) void droi_pool_kernel(
    const float* __restrict__ features,
    const float* __restrict__ rois,
    const float* __restrict__ offset,
    float* __restrict__ out)
{
    const int blk  = blockIdx.x;       // n * C + c
    const int n    = blk >> 8;         // / 256
    const int c    = blk & 255;
    const int lane = threadIdx.x;
    if (lane >= PH_ * PW_) return;
    const int ph = lane / PW_;
    const int pw = lane % PW_;

    // roi params (uniform across block -> scalar loads)
    const float r0  = rois[n * 5 + 0];
    const float x1r = rois[n * 5 + 1];
    const float y1r = rois[n * 5 + 2];
    const float x2r = rois[n * 5 + 3];
    const float y2r = rois[n * 5 + 4];
    const int   b   = (int)r0;

    const float sw    = x1r * SS_ - 0.5f;
    const float sh    = y1r * SS_ - 0.5f;
    const float rw    = fmaxf((x2r + 1.0f) * SS_ - 0.5f - sw, 0.1f);
    const float rh    = fmaxf((y2r + 1.0f) * SS_ - 0.5f - sh, 0.1f);
    const float bin_w = rw / PW_;
    const float bin_h = rh / PH_;
    const float sub_w = bin_w / SPP_;
    const float sub_h = bin_h / SPP_;

    const float offx = offset[((n * 2 + 0) * PH_ + ph) * PW_ + pw] * TRANS_STD_;
    const float offy = offset[((n * 2 + 1) * PH_ + ph) * PW_ + pw] * TRANS_STD_;

    const float bx = sw + (float)pw * bin_w + offx * rw;
    const float by = sh + (float)ph * bin_h + offy * rh;

    const float* __restrict__ f =
        features + (size_t)(b * C_ + c) * (size_t)(H_ * W_);

    float s = 0.0f;
    int cnt = 0;
#pragma unroll
    for (int ihs = 0; ihs < SPP_; ++ihs) {
#pragma unroll
        for (int iws = 0; iws < SPP_; ++iws) {
            const float x = bx + ((float)iws + 0.5f) * sub_w;
            const float y = by + ((float)ihs + 0.5f) * sub_h;
            const bool valid = (x > -0.5f) && (x < (float)W_ - 0.5f) &&
                               (y > -0.5f) && (y < (float)H_ - 0.5f);
            const float xc = fminf(fmaxf(x, 0.0f), (float)(W_ - 1));
            const float yc = fminf(fmaxf(y, 0.0f), (float)(H_ - 1));
            const float x0f = floorf(xc);
            const float y0f = floorf(yc);
            const float lx = xc - x0f;
            const float ly = yc - y0f;
            const int x0 = (int)x0f;
            const int y0 = (int)y0f;
            const int x1i = min(x0 + 1, W_ - 1);
            const int y1i = min(y0 + 1, H_ - 1);

            const float f00 = f[y0  * W_ + x0 ];
            const float f01 = f[y0  * W_ + x1i];
            const float f10 = f[y1i * W_ + x0 ];
            const float f11 = f[y1i * W_ + x1i];

            const float v = (1.0f - ly) * (1.0f - lx) * f00 +
                            (1.0f - ly) * lx          * f01 +
                            ly          * (1.0f - lx) * f10 +
                            ly          * lx          * f11;
            if (valid) { s += v; cnt += 1; }
        }
    }

    const float res = (cnt > 0) ? (s / (float)cnt) : 0.0f;
    out[(size_t)(n * C_ + c) * (PH_ * PW_) + lane] = res;
}

extern "C" void kernel_launch(void* const* d_in, const int* in_sizes, int n_in,
                              void* d_out, int out_size, void* d_ws, size_t ws_size,
                              hipStream_t stream) {
    const float* features = (const float*)d_in[0];
    const float* rois     = (const float*)d_in[1];
    const float* offset   = (const float*)d_in[2];
    float*       out      = (float*)d_out;

    dim3 grid(N_ * C_);   // 131072 blocks: one (n, c) pair each
    dim3 block(64);       // 1 wave; lanes 0..48 = 7x7 bins
    hipLaunchKernelGGL(droi_pool_kernel, grid, block, 0, stream,
                       features, rois, offset, out);
}

// Round 2
// 393.752 us; speedup vs baseline: 1.3103x; 1.3103x over previous
//
#include <hip/hip_runtime.h>
#include <hip/hip_fp16.h>

// Deformable RoI pooling (MMCV-style), forward only.
// features: (B=8, C=256, H=168, W=168) fp32 = 231 MB
// rois:     (N=512, 5)  [bidx, x1, y1, x2, y2]
// offset:   (N=512, 2, PH=7, PW=7)
// out:      (N, C, PH, PW) fp32
//
// Round 2 structure: one 256-thread block per (image b, channel c).
//   Phase 1: stream the 168x168 plane into LDS (fp16, 55.1 KB) with
//            coalesced float4 loads  -> each plane read from HBM exactly once.
//   Phase 2: all rois of image b sample bilinearly from the LDS plane.
// A tiny prologue kernel buckets rois by image into d_ws.

#define PH_ 7
#define PW_ 7
#define SPP_ 2
#define SS_ 0.0625f
#define TRANS_STD_ 0.1f
#define B_ 8
#define C_ 256
#define H_ 168
#define W_ 168
#define N_ 512
#define HW_ (H_ * W_)            // 28224
#define HW4_ (HW_ / 4)           // 7056 float4s per plane
#define RPC_ 5                   // rois per chunk (5*49 = 245 <= 256 threads)

// ---------------- prologue: bucket rois by image ----------------
// ws layout: int counts[8]; int lists[8][512];
__global__ __launch_bounds__(512) void build_roi_lists(
    const float* __restrict__ rois, int* __restrict__ ws)
{
    const int r = threadIdx.x;              // 512 threads, 1 block
    if (r < B_) ws[r] = 0;                  // ws is poisoned 0xAA each call
    __syncthreads();
    const int b = (int)rois[r * 5 + 0];
    const int pos = atomicAdd(&ws[b], 1);
    ws[B_ + b * N_ + pos] = r;
}

// ---------------- main kernel ----------------
__global__ __launch_bounds__(256) void droi_pool_lds(
    const float* __restrict__ features,
    const float* __restrict__ rois,
    const float* __restrict__ offset,
    float* __restrict__ out,
    const int* __restrict__ ws)
{
    __shared__ __half plane[HW_];           // 56,448 B -> 2 blocks/CU

    const int c   = blockIdx.x;             // channel
    const int b   = blockIdx.y;             // image
    const int tid = threadIdx.x;

    // ---- phase 1: plane -> LDS (fp16), coalesced float4 reads ----
    const float4* __restrict__ f4 =
        reinterpret_cast<const float4*>(features + (size_t)(b * C_ + c) * HW_);
    for (int i = tid; i < HW4_; i += 256) {
        const float4 v = f4[i];
        __half2 h0, h1;
        h0.x = __float2half(v.x); h0.y = __float2half(v.y);
        h1.x = __float2half(v.z); h1.y = __float2half(v.w);
        __half2* p = reinterpret_cast<__half2*>(&plane[i * 4]);
        p[0] = h0;
        p[1] = h1;
    }
    __syncthreads();

    // ---- phase 2: all rois of image b sample from LDS ----
    const int cnt_b = ws[b];
    const int* __restrict__ list = ws + B_ + b * N_;

    const int q   = tid / 49;               // roi slot within chunk (0..5)
    const int bin = tid - q * 49;           // 0..48
    const int ph  = bin / PW_;
    const int pw  = bin - ph * PW_;
    const bool lane_ok = (q < RPC_);

    for (int base = 0; base < cnt_b; base += RPC_) {
        const int idx    = base + q;
        const bool active = lane_ok && (idx < cnt_b);
        const int r = list[active ? idx : 0];

        const float x1r = rois[r * 5 + 1];
        const float y1r = rois[r * 5 + 2];
        const float x2r = rois[r * 5 + 3];
        const float y2r = rois[r * 5 + 4];

        const float sw    = x1r * SS_ - 0.5f;
        const float sh    = y1r * SS_ - 0.5f;
        const float rw    = fmaxf((x2r + 1.0f) * SS_ - 0.5f - sw, 0.1f);
        const float rh    = fmaxf((y2r + 1.0f) * SS_ - 0.5f - sh, 0.1f);
        const float bin_w = rw * (1.0f / PW_);
        const float bin_h = rh * (1.0f / PH_);
        const float sub_w = bin_w * (1.0f / SPP_);
        const float sub_h = bin_h * (1.0f / SPP_);

        const float offx = offset[((r * 2 + 0) * PH_ + ph) * PW_ + pw] * TRANS_STD_;
        const float offy = offset[((r * 2 + 1) * PH_ + ph) * PW_ + pw] * TRANS_STD_;

        const float bx = sw + (float)pw * bin_w + offx * rw;
        const float by = sh + (float)ph * bin_h + offy * rh;

        float s = 0.0f;
        int cnt = 0;
#pragma unroll
        for (int ihs = 0; ihs < SPP_; ++ihs) {
#pragma unroll
            for (int iws = 0; iws < SPP_; ++iws) {
                const float x = bx + ((float)iws + 0.5f) * sub_w;
                const float y = by + ((float)ihs + 0.5f) * sub_h;
                const bool valid = (x > -0.5f) && (x < (float)W_ - 0.5f) &&
                                   (y > -0.5f) && (y < (float)H_ - 0.5f);
                const float xc = fminf(fmaxf(x, 0.0f), (float)(W_ - 1));
                const float yc = fminf(fmaxf(y, 0.0f), (float)(H_ - 1));
                const float x0f = floorf(xc);
                const float y0f = floorf(yc);
                const float lx = xc - x0f;
                const float ly = yc - y0f;
                const int x0 = (int)x0f;
                const int y0 = (int)y0f;
                const int x1i = min(x0 + 1, W_ - 1);
                const int y1i = min(y0 + 1, H_ - 1);

                const float f00 = __half2float(plane[y0  * W_ + x0 ]);
                const float f01 = __half2float(plane[y0  * W_ + x1i]);
                const float f10 = __half2float(plane[y1i * W_ + x0 ]);
                const float f11 = __half2float(plane[y1i * W_ + x1i]);

                const float v = (1.0f - ly) * (1.0f - lx) * f00 +
                                (1.0f - ly) * lx          * f01 +
                                ly          * (1.0f - lx) * f10 +
                                ly          * lx          * f11;
                if (valid) { s += v; cnt += 1; }
            }
        }

        if (active) {
            const float res = (cnt > 0) ? (s / (float)cnt) : 0.0f;
            out[((size_t)r * C_ + c) * (PH_ * PW_) + bin] = res;
        }
    }
}

// ---------------- fallback (round-1 kernel) if ws too small ----------------
__global__ __launch_bounds__(64) void droi_pool_fallback(
    const float* __restrict__ features,
    const float* __restrict__ rois,
    const float* __restrict__ offset,
    float* __restrict__ out)
{
    const int blk  = blockIdx.x;
    const int n    = blk >> 8;
    const int c    = blk & 255;
    const int lane = threadIdx.x;
    if (lane >= PH_ * PW_) return;
    const int ph = lane / PW_;
    const int pw = lane % PW_;

    const float r0  = rois[n * 5 + 0];
    const float x1r = rois[n * 5 + 1];
    const float y1r = rois[n * 5 + 2];
    const float x2r = rois[n * 5 + 3];
    const float y2r = rois[n * 5 + 4];
    const int   b   = (int)r0;

    const float sw    = x1r * SS_ - 0.5f;
    const float sh    = y1r * SS_ - 0.5f;
    const float rw    = fmaxf((x2r + 1.0f) * SS_ - 0.5f - sw, 0.1f);
    const float rh    = fmaxf((y2r + 1.0f) * SS_ - 0.5f - sh, 0.1f);
    const float bin_w = rw / PW_;
    const float bin_h = rh / PH_;
    const float sub_w = bin_w / SPP_;
    const float sub_h = bin_h / SPP_;

    const float offx = offset[((n * 2 + 0) * PH_ + ph) * PW_ + pw] * TRANS_STD_;
    const float offy = offset[((n * 2 + 1) * PH_ + ph) * PW_ + pw] * TRANS_STD_;

    const float bx = sw + (float)pw * bin_w + offx * rw;
    const float by = sh + (float)ph * bin_h + offy * rh;

    const float* __restrict__ f =
        features + (size_t)(b * C_ + c) * (size_t)HW_;

    float s = 0.0f;
    int cnt = 0;
#pragma unroll
    for (int ihs = 0; ihs < SPP_; ++ihs) {
#pragma unroll
        for (int iws = 0; iws < SPP_; ++iws) {
            const float x = bx + ((float)iws + 0.5f) * sub_w;
            const float y = by + ((float)ihs + 0.5f) * sub_h;
            const bool valid = (x > -0.5f) && (x < (float)W_ - 0.5f) &&
                               (y > -0.5f) && (y < (float)H_ - 0.5f);
            const float xc = fminf(fmaxf(x, 0.0f), (float)(W_ - 1));
            const float yc = fminf(fmaxf(y, 0.0f), (float)(H_ - 1));
            const float x0f = floorf(xc);
            const float y0f = floorf(yc);
            const float lx = xc - x0f;
            const float ly = yc - y0f;
            const int x0 = (int)x0f;
            const int y0 = (int)y0f;
            const int x1i = min(x0 + 1, W_ - 1);
            const int y1i = min(y0 + 1, H_ - 1);
            const float f00 = f[y0  * W_ + x0 ];
            const float f01 = f[y0  * W_ + x1i];
            const float f10 = f[y1i * W_ + x0 ];
            const float f11 = f[y1i * W_ + x1i];
            const float v = (1.0f - ly) * (1.0f - lx) * f00 +
                            (1.0f - ly) * lx          * f01 +
                            ly          * (1.0f - lx) * f10 +
                            ly          * lx          * f11;
            if (valid) { s += v; cnt += 1; }
        }
    }
    const float res = (cnt > 0) ? (s / (float)cnt) : 0.0f;
    out[(size_t)(n * C_ + c) * (PH_ * PW_) + lane] = res;
}

extern "C" void kernel_launch(void* const* d_in, const int* in_sizes, int n_in,
                              void* d_out, int out_size, void* d_ws, size_t ws_size,
                              hipStream_t stream) {
    const float* features = (const float*)d_in[0];
    const float* rois     = (const float*)d_in[1];
    const float* offset   = (const float*)d_in[2];
    float*       out      = (float*)d_out;

    const size_t ws_needed = (size_t)(B_ + B_ * N_) * sizeof(int);  // 16,416 B
    if (ws_size >= ws_needed) {
        int* ws = (int*)d_ws;
        hipLaunchKernelGGL(build_roi_lists, dim3(1), dim3(N_), 0, stream,
                           rois, ws);
        // grid: x = channel (256), y = image (8); 2048 blocks, 2 resident/CU
        hipLaunchKernelGGL(droi_pool_lds, dim3(C_, B_), dim3(256), 0, stream,
                           features, rois, offset, out, ws);
    } else {
        hipLaunchKernelGGL(droi_pool_fallback, dim3(N_ * C_), dim3(64), 0, stream,
                           features, rois, offset, out);
    }
}

// Round 3
// 357.389 us; speedup vs baseline: 1.4436x; 1.1017x over previous
//
#include <hip/hip_runtime.h>
#include <hip/hip_fp16.h>

// Deformable RoI pooling (MMCV-style), forward only.
// features: (B=8, C=256, H=168, W=168) fp32 = 231 MB
// rois:     (N=512, 5)  [bidx, x1, y1, x2, y2]
// offset:   (N=512, 2, PH=7, PW=7)
// out:      (N, C, PH, PW) fp32
//
// Round 3: same (image, channel)-plane-in-LDS structure as round 2, but
// 512-thread blocks. LDS 56.8 KB -> still 2 resident blocks/CU, now
// 16 waves/CU (50% occupancy) instead of 8 (25%) -> hides LDS/global
// latency that dominated round 2 (VALUBusy 21.6%, Occupancy 22.5%).

#define PH_ 7
#define PW_ 7
#define SPP_ 2
#define SS_ 0.0625f
#define TRANS_STD_ 0.1f
#define B_ 8
#define C_ 256
#define H_ 168
#define W_ 168
#define N_ 512
#define HW_ (H_ * W_)            // 28224
#define HW4_ (HW_ / 4)           // 7056 float4s per plane
#define BLK_ 512
#define RPC_ 10                  // rois per chunk (10*49 = 490 <= 512)

// ---------------- prologue: bucket rois by image ----------------
// ws layout: int counts[8]; int lists[8][512];
__global__ __launch_bounds__(512) void build_roi_lists(
    const float* __restrict__ rois, int* __restrict__ ws)
{
    const int r = threadIdx.x;              // 512 threads, 1 block
    if (r < B_) ws[r] = 0;                  // ws is poisoned 0xAA each call
    __syncthreads();
    const int b = (int)rois[r * 5 + 0];
    const int pos = atomicAdd(&ws[b], 1);
    ws[B_ + b * N_ + pos] = r;
}

// ---------------- main kernel ----------------
__global__ __launch_bounds__(BLK_) void droi_pool_lds(
    const float* __restrict__ features,
    const float* __restrict__ rois,
    const float* __restrict__ offset,
    float* __restrict__ out,
    const int* __restrict__ ws)
{
    __shared__ __half plane[HW_];           // 56,448 B -> 2 blocks/CU

    const int c   = blockIdx.x;             // channel
    const int b   = blockIdx.y;             // image
    const int tid = threadIdx.x;

    // ---- phase 1: plane -> LDS (fp16), coalesced float4 reads ----
    const float4* __restrict__ f4 =
        reinterpret_cast<const float4*>(features + (size_t)(b * C_ + c) * HW_);
    {
        const int full = HW4_ / BLK_;       // 13 full strides
#pragma unroll 4
        for (int k = 0; k < full; ++k) {
            const int i = tid + k * BLK_;
            const float4 v = f4[i];
            union { __half2 h[2]; float2 f2; } u;
            u.h[0].x = __float2half(v.x); u.h[0].y = __float2half(v.y);
            u.h[1].x = __float2half(v.z); u.h[1].y = __float2half(v.w);
            *reinterpret_cast<float2*>(&plane[i * 4]) = u.f2;
        }
        const int i = tid + full * BLK_;    // tail: 7056 - 13*512 = 400
        if (i < HW4_) {
            const float4 v = f4[i];
            union { __half2 h[2]; float2 f2; } u;
            u.h[0].x = __float2half(v.x); u.h[0].y = __float2half(v.y);
            u.h[1].x = __float2half(v.z); u.h[1].y = __float2half(v.w);
            *reinterpret_cast<float2*>(&plane[i * 4]) = u.f2;
        }
    }
    __syncthreads();

    // ---- phase 2: all rois of image b sample from LDS ----
    const int cnt_b = ws[b];
    const int* __restrict__ list = ws + B_ + b * N_;

    const int q   = tid / 49;               // roi slot within chunk (0..10)
    const int bin = tid - q * 49;           // 0..48
    const int ph  = bin / PW_;
    const int pw  = bin - ph * PW_;
    const bool lane_ok = (q < RPC_);

    for (int base = 0; base < cnt_b; base += RPC_) {
        const int idx     = base + q;
        const bool active = lane_ok && (idx < cnt_b);
        const int r = list[active ? idx : 0];

        const float x1r = rois[r * 5 + 1];
        const float y1r = rois[r * 5 + 2];
        const float x2r = rois[r * 5 + 3];
        const float y2r = rois[r * 5 + 4];

        const float sw    = x1r * SS_ - 0.5f;
        const float sh    = y1r * SS_ - 0.5f;
        const float rw    = fmaxf((x2r + 1.0f) * SS_ - 0.5f - sw, 0.1f);
        const float rh    = fmaxf((y2r + 1.0f) * SS_ - 0.5f - sh, 0.1f);
        const float bin_w = rw * (1.0f / PW_);
        const float bin_h = rh * (1.0f / PH_);
        const float sub_w = bin_w * (1.0f / SPP_);
        const float sub_h = bin_h * (1.0f / SPP_);

        const float offx = offset[((r * 2 + 0) * PH_ + ph) * PW_ + pw] * TRANS_STD_;
        const float offy = offset[((r * 2 + 1) * PH_ + ph) * PW_ + pw] * TRANS_STD_;

        const float bx = sw + (float)pw * bin_w + offx * rw;
        const float by = sh + (float)ph * bin_h + offy * rh;

        float s = 0.0f;
        int cnt = 0;
#pragma unroll
        for (int ihs = 0; ihs < SPP_; ++ihs) {
#pragma unroll
            for (int iws = 0; iws < SPP_; ++iws) {
                const float x = bx + ((float)iws + 0.5f) * sub_w;
                const float y = by + ((float)ihs + 0.5f) * sub_h;
                const bool valid = (x > -0.5f) && (x < (float)W_ - 0.5f) &&
                                   (y > -0.5f) && (y < (float)H_ - 0.5f);
                const float xc = fminf(fmaxf(x, 0.0f), (float)(W_ - 1));
                const float yc = fminf(fmaxf(y, 0.0f), (float)(H_ - 1));
                const float x0f = floorf(xc);
                const float y0f = floorf(yc);
                const float lx = xc - x0f;
                const float ly = yc - y0f;
                const int x0 = (int)x0f;
                const int y0 = (int)y0f;
                const int x1i = min(x0 + 1, W_ - 1);
                const int y1i = min(y0 + 1, H_ - 1);

                const float f00 = __half2float(plane[y0  * W_ + x0 ]);
                const float f01 = __half2float(plane[y0  * W_ + x1i]);
                const float f10 = __half2float(plane[y1i * W_ + x0 ]);
                const float f11 = __half2float(plane[y1i * W_ + x1i]);

                const float v = (1.0f - ly) * (1.0f - lx) * f00 +
                                (1.0f - ly) * lx          * f01 +
                                ly          * (1.0f - lx) * f10 +
                                ly          * lx          * f11;
                if (valid) { s += v; cnt += 1; }
            }
        }

        if (active) {
            const float res = (cnt > 0) ? (s / (float)cnt) : 0.0f;
            out[((size_t)r * C_ + c) * (PH_ * PW_) + bin] = res;
        }
    }
}

// ---------------- fallback (round-1 kernel) if ws too small ----------------
__global__ __launch_bounds__(64) void droi_pool_fallback(
    const float* __restrict__ features,
    const float* __restrict__ rois,
    const float* __restrict__ offset,
    float* __restrict__ out)
{
    const int blk  = blockIdx.x;
    const int n    = blk >> 8;
    const int c    = blk & 255;
    const int lane = threadIdx.x;
    if (lane >= PH_ * PW_) return;
    const int ph = lane / PW_;
    const int pw = lane % PW_;

    const float r0  = rois[n * 5 + 0];
    const float x1r = rois[n * 5 + 1];
    const float y1r = rois[n * 5 + 2];
    const float x2r = rois[n * 5 + 3];
    const float y2r = rois[n * 5 + 4];
    const int   b   = (int)r0;

    const float sw    = x1r * SS_ - 0.5f;
    const float sh    = y1r * SS_ - 0.5f;
    const float rw    = fmaxf((x2r + 1.0f) * SS_ - 0.5f - sw, 0.1f);
    const float rh    = fmaxf((y2r + 1.0f) * SS_ - 0.5f - sh, 0.1f);
    const float bin_w = rw / PW_;
    const float bin_h = rh / PH_;
    const float sub_w = bin_w / SPP_;
    const float sub_h = bin_h / SPP_;

    const float offx = offset[((n * 2 + 0) * PH_ + ph) * PW_ + pw] * TRANS_STD_;
    const float offy = offset[((n * 2 + 1) * PH_ + ph) * PW_ + pw] * TRANS_STD_;

    const float bx = sw + (float)pw * bin_w + offx * rw;
    const float by = sh + (float)ph * bin_h + offy * rh;

    const float* __restrict__ f =
        features + (size_t)(b * C_ + c) * (size_t)HW_;

    float s = 0.0f;
    int cnt = 0;
#pragma unroll
    for (int ihs = 0; ihs < SPP_; ++ihs) {
#pragma unroll
        for (int iws = 0; iws < SPP_; ++iws) {
            const float x = bx + ((float)iws + 0.5f) * sub_w;
            const float y = by + ((float)ihs + 0.5f) * sub_h;
            const bool valid = (x > -0.5f) && (x < (float)W_ - 0.5f) &&
                               (y > -0.5f) && (y < (float)H_ - 0.5f);
            const float xc = fminf(fmaxf(x, 0.0f), (float)(W_ - 1));
            const float yc = fminf(fmaxf(y, 0.0f), (float)(H_ - 1));
            const float x0f = floorf(xc);
            const float y0f = floorf(yc);
            const float lx = xc - x0f;
            const float ly = yc - y0f;
            const int x0 = (int)x0f;
            const int y0 = (int)y0f;
            const int x1i = min(x0 + 1, W_ - 1);
            const int y1i = min(y0 + 1, H_ - 1);
            const float f00 = f[y0  * W_ + x0 ];
            const float f01 = f[y0  * W_ + x1i];
            const float f10 = f[y1i * W_ + x0 ];
            const float f11 = f[y1i * W_ + x1i];
            const float v = (1.0f - ly) * (1.0f - lx) * f00 +
                            (1.0f - ly) * lx          * f01 +
                            ly          * (1.0f - lx) * f10 +
                            ly          * lx          * f11;
            if (valid) { s += v; cnt += 1; }
        }
    }
    const float res = (cnt > 0) ? (s / (float)cnt) : 0.0f;
    out[(size_t)(n * C_ + c) * (PH_ * PW_) + lane] = res;
}

extern "C" void kernel_launch(void* const* d_in, const int* in_sizes, int n_in,
                              void* d_out, int out_size, void* d_ws, size_t ws_size,
                              hipStream_t stream) {
    const float* features = (const float*)d_in[0];
    const float* rois     = (const float*)d_in[1];
    const float* offset   = (const float*)d_in[2];
    float*       out      = (float*)d_out;

    const size_t ws_needed = (size_t)(B_ + B_ * N_) * sizeof(int);  // 16,416 B
    if (ws_size >= ws_needed) {
        int* ws = (int*)d_ws;
        hipLaunchKernelGGL(build_roi_lists, dim3(1), dim3(N_), 0, stream,
                           rois, ws);
        // grid: x = channel (256), y = image (8); 2048 blocks, 2 resident/CU,
        // 512 threads each -> 16 waves/CU
        hipLaunchKernelGGL(droi_pool_lds, dim3(C_, B_), dim3(BLK_), 0, stream,
                           features, rois, offset, out, ws);
    } else {
        hipLaunchKernelGGL(droi_pool_fallback, dim3(N_ * C_), dim3(64), 0, stream,
                           features, rois, offset, out);
    }
}

// Round 4
// 345.995 us; speedup vs baseline: 1.4911x; 1.0329x over previous
//
#include <hip/hip_runtime.h>
#include <hip/hip_fp16.h>

// Deformable RoI pooling (MMCV-style), forward only.
// features: (B=8, C=256, H=168, W=168) fp32 = 231 MB
// rois:     (N=512, 5)  [bidx, x1, y1, x2, y2]
// offset:   (N=512, 2, PH=7, PW=7)
// out:      (N, C, PH, PW) fp32
//
// Round 4:
//  - prologue precomputes per-(roi,bin,subsample) descriptors
//    {packed addr/dx/dy, lx, ly, scale} (scale = 1/valid_cnt, 0 if invalid)
//    -> main kernel phase 2 is desc-load + 4 LDS reads + ~15 VALU.
//  - main kernel: 1024-thread blocks, __launch_bounds__(1024, 8) to force
//    VGPR <= 64 -> 2 blocks/CU (LDS 2x56.8 KB) -> 32 waves/CU (100%).

#define PH_ 7
#define PW_ 7
#define SPP_ 2
#define SS_ 0.0625f
#define TRANS_STD_ 0.1f
#define B_ 8
#define C_ 256
#define H_ 168
#define W_ 168
#define N_ 512
#define HW_ (H_ * W_)            // 28224
#define HW4_ (HW_ / 4)           // 7056 float4s per plane
#define BINS_ (PH_ * PW_)        // 49
#define NSUB_ (SPP_ * SPP_)      // 4
#define BLK_ 1024
#define RPC_ 20                  // rois per chunk (20*49 = 980 <= 1024)

// ws layout (ints): counts[8] | lists[8][512] | desc as float4[N][NSUB][BINS]
#define WS_LIST_OFF_  B_
#define WS_DESC_OFF_I (B_ + B_ * N_)                 // 4104 ints = 16416 B (16B-aligned)
#define DESC_FLOATS_  (N_ * NSUB_ * BINS_ * 4)       // 401408 floats
#define WS_NEEDED_    ((size_t)(WS_DESC_OFF_I) * 4 + (size_t)DESC_FLOATS_ * 4)

// ---------------- prologue 1: bucket rois by image ----------------
__global__ __launch_bounds__(512) void build_roi_lists(
    const float* __restrict__ rois, int* __restrict__ ws)
{
    const int r = threadIdx.x;              // 512 threads, 1 block
    if (r < B_) ws[r] = 0;                  // ws is poisoned 0xAA each call
    __syncthreads();
    const int b = (int)rois[r * 5 + 0];
    const int pos = atomicAdd(&ws[b], 1);
    ws[WS_LIST_OFF_ + b * N_ + pos] = r;
}

// ---------------- prologue 2: sample descriptors ----------------
// one block per roi; lanes 0..48 = bins; each lane does 4 subsamples.
__global__ __launch_bounds__(64) void build_desc(
    const float* __restrict__ rois,
    const float* __restrict__ offset,
    float4* __restrict__ desc)              // [N][NSUB][BINS]
{
    const int r   = blockIdx.x;
    const int bin = threadIdx.x;
    if (bin >= BINS_) return;
    const int ph = bin / PW_;
    const int pw = bin - ph * PW_;

    const float x1r = rois[r * 5 + 1];
    const float y1r = rois[r * 5 + 2];
    const float x2r = rois[r * 5 + 3];
    const float y2r = rois[r * 5 + 4];

    const float sw    = x1r * SS_ - 0.5f;
    const float sh    = y1r * SS_ - 0.5f;
    const float rw    = fmaxf((x2r + 1.0f) * SS_ - 0.5f - sw, 0.1f);
    const float rh    = fmaxf((y2r + 1.0f) * SS_ - 0.5f - sh, 0.1f);
    const float bin_w = rw * (1.0f / PW_);
    const float bin_h = rh * (1.0f / PH_);
    const float sub_w = bin_w * (1.0f / SPP_);
    const float sub_h = bin_h * (1.0f / SPP_);

    const float offx = offset[((r * 2 + 0) * PH_ + ph) * PW_ + pw] * TRANS_STD_;
    const float offy = offset[((r * 2 + 1) * PH_ + ph) * PW_ + pw] * TRANS_STD_;

    const float bx = sw + (float)pw * bin_w + offx * rw;
    const float by = sh + (float)ph * bin_h + offy * rh;

    unsigned pack[NSUB_];
    float lxs[NSUB_], lys[NSUB_];
    int   vals[NSUB_];
    int   cnt = 0;
#pragma unroll
    for (int s = 0; s < NSUB_; ++s) {
        const int ihs = s >> 1;             // sub index order: (ih, iw)
        const int iws = s & 1;
        const float x = bx + ((float)iws + 0.5f) * sub_w;
        const float y = by + ((float)ihs + 0.5f) * sub_h;
        const int valid = (x > -0.5f) && (x < (float)W_ - 0.5f) &&
                          (y > -0.5f) && (y < (float)H_ - 0.5f);
        const float xc = fminf(fmaxf(x, 0.0f), (float)(W_ - 1));
        const float yc = fminf(fmaxf(y, 0.0f), (float)(H_ - 1));
        const float x0f = floorf(xc);
        const float y0f = floorf(yc);
        const int x0 = (int)x0f;
        const int y0 = (int)y0f;
        const int dx = (x0 + 1 <= W_ - 1) ? 1 : 0;
        const int dy = (y0 + 1 <= H_ - 1) ? 1 : 0;
        pack[s] = (unsigned)(y0 * W_ + x0) | ((unsigned)dx << 15) |
                  ((unsigned)dy << 16);
        lxs[s] = xc - x0f;
        lys[s] = yc - y0f;
        vals[s] = valid;
        cnt += valid;
    }
    const float inv = (cnt > 0) ? (1.0f / (float)cnt) : 0.0f;
#pragma unroll
    for (int s = 0; s < NSUB_; ++s) {
        float4 d;
        d.x = __uint_as_float(pack[s]);
        d.y = lxs[s];
        d.z = lys[s];
        d.w = vals[s] ? inv : 0.0f;
        desc[((size_t)r * NSUB_ + s) * BINS_ + bin] = d;
    }
}

// ---------------- main kernel ----------------
__global__ __launch_bounds__(BLK_, 8) void droi_pool_lds(
    const float* __restrict__ features,
    float* __restrict__ out,
    const int* __restrict__ ws)
{
    __shared__ __half plane[HW_];           // 56,448 B -> 2 blocks/CU @1024 thr

    const int c   = blockIdx.x;             // channel
    const int b   = blockIdx.y;             // image
    const int tid = threadIdx.x;

    // ---- phase 1: plane -> LDS (fp16), coalesced float4 reads ----
    const float4* __restrict__ f4 =
        reinterpret_cast<const float4*>(features + (size_t)(b * C_ + c) * HW_);
    for (int i = tid; i < HW4_; i += BLK_) {
        const float4 v = f4[i];
        union { __half2 h[2]; float2 f2; } u;
        u.h[0].x = __float2half(v.x); u.h[0].y = __float2half(v.y);
        u.h[1].x = __float2half(v.z); u.h[1].y = __float2half(v.w);
        *reinterpret_cast<float2*>(&plane[i * 4]) = u.f2;
    }
    __syncthreads();

    // ---- phase 2: rois of image b sample from LDS via descriptors ----
    const int cnt_b = ws[b];
    const int* __restrict__ list = ws + WS_LIST_OFF_ + b * N_;
    const float4* __restrict__ desc =
        reinterpret_cast<const float4*>(ws + WS_DESC_OFF_I);

    const int q   = tid / BINS_;            // roi slot within chunk
    const int bin = tid - q * BINS_;        // 0..48
    const bool lane_ok = (q < RPC_);

    for (int base = 0; base < cnt_b; base += RPC_) {
        const int idx     = base + q;
        const bool active = lane_ok && (idx < cnt_b);
        const int r = list[active ? idx : 0];

        float acc = 0.0f;
#pragma unroll
        for (int s = 0; s < NSUB_; ++s) {
            const float4 d = desc[((size_t)r * NSUB_ + s) * BINS_ + bin];
            const unsigned pk = __float_as_uint(d.x);
            const int a00 = (int)(pk & 0x7FFFu);
            const int dx  = (int)((pk >> 15) & 1u);
            const int a10 = a00 + (int)((pk >> 16) & 1u) * W_;
            const float lx = d.y;
            const float ly = d.z;

            const float f00 = __half2float(plane[a00]);
            const float f01 = __half2float(plane[a00 + dx]);
            const float f10 = __half2float(plane[a10]);
            const float f11 = __half2float(plane[a10 + dx]);

            const float top = f00 + lx * (f01 - f00);
            const float bot = f10 + lx * (f11 - f10);
            acc += d.w * (top + ly * (bot - top));
        }

        if (active) {
            out[((size_t)r * C_ + c) * BINS_ + bin] = acc;
        }
    }
}

// ---------------- fallback (round-1 kernel) if ws too small ----------------
__global__ __launch_bounds__(64) void droi_pool_fallback(
    const float* __restrict__ features,
    const float* __restrict__ rois,
    const float* __restrict__ offset,
    float* __restrict__ out)
{
    const int blk  = blockIdx.x;
    const int n    = blk >> 8;
    const int c    = blk & 255;
    const int lane = threadIdx.x;
    if (lane >= BINS_) return;
    const int ph = lane / PW_;
    const int pw = lane % PW_;

    const float r0  = rois[n * 5 + 0];
    const float x1r = rois[n * 5 + 1];
    const float y1r = rois[n * 5 + 2];
    const float x2r = rois[n * 5 + 3];
    const float y2r = rois[n * 5 + 4];
    const int   b   = (int)r0;

    const float sw    = x1r * SS_ - 0.5f;
    const float sh    = y1r * SS_ - 0.5f;
    const float rw    = fmaxf((x2r + 1.0f) * SS_ - 0.5f - sw, 0.1f);
    const float rh    = fmaxf((y2r + 1.0f) * SS_ - 0.5f - sh, 0.1f);
    const float bin_w = rw / PW_;
    const float bin_h = rh / PH_;
    const float sub_w = bin_w / SPP_;
    const float sub_h = bin_h / SPP_;

    const float offx = offset[((n * 2 + 0) * PH_ + ph) * PW_ + pw] * TRANS_STD_;
    const float offy = offset[((n * 2 + 1) * PH_ + ph) * PW_ + pw] * TRANS_STD_;

    const float bx = sw + (float)pw * bin_w + offx * rw;
    const float by = sh + (float)ph * bin_h + offy * rh;

    const float* __restrict__ f =
        features + (size_t)(b * C_ + c) * (size_t)HW_;

    float s = 0.0f;
    int cnt = 0;
#pragma unroll
    for (int ihs = 0; ihs < SPP_; ++ihs) {
#pragma unroll
        for (int iws = 0; iws < SPP_; ++iws) {
            const float x = bx + ((float)iws + 0.5f) * sub_w;
            const float y = by + ((float)ihs + 0.5f) * sub_h;
            const bool valid = (x > -0.5f) && (x < (float)W_ - 0.5f) &&
                               (y > -0.5f) && (y < (float)H_ - 0.5f);
            const float xc = fminf(fmaxf(x, 0.0f), (float)(W_ - 1));
            const float yc = fminf(fmaxf(y, 0.0f), (float)(H_ - 1));
            const float x0f = floorf(xc);
            const float y0f = floorf(yc);
            const float lx = xc - x0f;
            const float ly = yc - y0f;
            const int x0 = (int)x0f;
            const int y0 = (int)y0f;
            const int x1i = min(x0 + 1, W_ - 1);
            const int y1i = min(y0 + 1, H_ - 1);
            const float f00 = f[y0  * W_ + x0 ];
            const float f01 = f[y0  * W_ + x1i];
            const float f10 = f[y1i * W_ + x0 ];
            const float f11 = f[y1i * W_ + x1i];
            const float v = (1.0f - ly) * (1.0f - lx) * f00 +
                            (1.0f - ly) * lx          * f01 +
                            ly          * (1.0f - lx) * f10 +
                            ly          * lx          * f11;
            if (valid) { s += v; cnt += 1; }
        }
    }
    const float res = (cnt > 0) ? (s / (float)cnt) : 0.0f;
    out[(size_t)(n * C_ + c) * BINS_ + lane] = res;
}

extern "C" void kernel_launch(void* const* d_in, const int* in_sizes, int n_in,
                              void* d_out, int out_size, void* d_ws, size_t ws_size,
                              hipStream_t stream) {
    const float* features = (const float*)d_in[0];
    const float* rois     = (const float*)d_in[1];
    const float* offset   = (const float*)d_in[2];
    float*       out      = (float*)d_out;

    if (ws_size >= WS_NEEDED_) {
        int* ws = (int*)d_ws;
        float4* desc = reinterpret_cast<float4*>(ws + WS_DESC_OFF_I);
        hipLaunchKernelGGL(build_roi_lists, dim3(1), dim3(N_), 0, stream,
                           rois, ws);
        hipLaunchKernelGGL(build_desc, dim3(N_), dim3(64), 0, stream,
                           rois, offset, desc);
        // grid: x = channel (256), y = image (8); 2048 blocks, 2 resident/CU,
        // 1024 threads each -> 32 waves/CU (100%)
        hipLaunchKernelGGL(droi_pool_lds, dim3(C_, B_), dim3(BLK_), 0, stream,
                           features, out, ws);
    } else {
        hipLaunchKernelGGL(droi_pool_fallback, dim3(N_ * C_), dim3(64), 0, stream,
                           features, rois, offset, out);
    }
}